// Round 3
// baseline (425.589 us; speedup 1.0000x reference)
//
#include <hip/hip_runtime.h>
#include <math.h>

#define N_ROWS 4096
#define N_COLS 32000
#define BLK 256

typedef float vf4 __attribute__((ext_vector_type(4)));

// gamma buckets: pt >= 0.5 -> 3, 0.2 <= pt < 0.5 -> 3, pt < 0.2 -> 5
// so gamma == 5 iff pt < 0.2, else 3.

__device__ __forceinline__ void online_update(float& m, float& s, vf4 v) {
    float vmax = fmaxf(fmaxf(v.x, v.y), fmaxf(v.z, v.w));
    float nm = fmaxf(m, vmax);                 // branchless
    s = s * __expf(m - nm)
      + __expf(v.x - nm) + __expf(v.y - nm)
      + __expf(v.z - nm) + __expf(v.w - nm);
    m = nm;
}

__global__ __launch_bounds__(BLK) void focal_fused_kernel(
    const float* __restrict__ inp,
    const int* __restrict__ target,
    float* row_loss,            // ws: N_ROWS floats
    unsigned* ticket,           // ws: 1 uint (zeroed via memsetAsync each call)
    float* out)
{
    const int row = blockIdx.x;
    const int tid = threadIdx.x;
    const float* __restrict__ rp = inp + (size_t)row * N_COLS;
    const vf4* __restrict__ rp4 = (const vf4*)rp;
    const int nvec = N_COLS / 4;  // 8000, exact

    // two independent accumulator pairs -> deeper load pipeline
    float m0 = -3.0e38f, s0 = 0.0f;
    float m1 = -3.0e38f, s1 = 0.0f;

    int i = tid;
    for (; i + BLK < nvec; i += 2 * BLK) {
        vf4 a = __builtin_nontemporal_load(rp4 + i);
        vf4 b = __builtin_nontemporal_load(rp4 + i + BLK);
        online_update(m0, s0, a);
        online_update(m1, s1, b);
    }
    if (i < nvec) {
        vf4 a = __builtin_nontemporal_load(rp4 + i);
        online_update(m0, s0, a);
    }

    // merge the two accumulators
    float m = fmaxf(m0, m1);
    float s = s0 * __expf(m0 - m) + s1 * __expf(m1 - m);

    // ---- wave (64-lane) butterfly reduce of (m, s) ----
    #pragma unroll
    for (int off = 32; off > 0; off >>= 1) {
        float om = __shfl_xor(m, off, 64);
        float os = __shfl_xor(s, off, 64);
        float nm = fmaxf(m, om);
        s = s * __expf(m - nm) + os * __expf(om - nm);
        m = nm;
    }

    // ---- cross-wave combine via LDS (4 waves) ----
    __shared__ float sm[BLK / 64];
    __shared__ float ss[BLK / 64];
    __shared__ int amLast;
    if ((tid & 63) == 0) {
        sm[tid >> 6] = m;
        ss[tid >> 6] = s;
    }
    __syncthreads();

    if (tid == 0) {
        float M = sm[0];
        float S = ss[0];
        #pragma unroll
        for (int w = 1; w < BLK / 64; ++w) {
            float om = sm[w], os = ss[w];
            float nm = fmaxf(M, om);
            S = S * __expf(M - nm) + os * __expf(om - nm);
            M = nm;
        }
        const int t = target[row];
        const float x = rp[t];
        const float logpt = x - M - __logf(S);
        const float pt = __expf(logpt);
        const float u = 1.0f - pt;
        const float u3 = u * u * u;
        const float g = (pt < 0.2f) ? (u3 * u * u) : u3;  // (1-pt)^gamma
        const float loss = -g * logpt;

        // release-store row loss (agent scope -> visible cross-XCD), then ticket
        __hip_atomic_store(&row_loss[row], loss,
                           __ATOMIC_RELEASE, __HIP_MEMORY_SCOPE_AGENT);
        unsigned old = __hip_atomic_fetch_add(ticket, 1u,
                           __ATOMIC_ACQ_REL, __HIP_MEMORY_SCOPE_AGENT);
        amLast = (old == N_ROWS - 1) ? 1 : 0;
    }
    __syncthreads();

    // last-arriving block: fixed-order deterministic mean over all rows
    if (amLast) {
        float acc = 0.0f;
        for (int r = tid; r < N_ROWS; r += BLK)
            acc += __hip_atomic_load(&row_loss[r],
                       __ATOMIC_RELAXED, __HIP_MEMORY_SCOPE_AGENT);

        #pragma unroll
        for (int off = 32; off > 0; off >>= 1)
            acc += __shfl_xor(acc, off, 64);

        if ((tid & 63) == 0) sm[tid >> 6] = acc;
        __syncthreads();

        if (tid == 0) {
            float total = 0.0f;
            #pragma unroll
            for (int w = 0; w < BLK / 64; ++w) total += sm[w];
            out[0] = total * (1.0f / (float)N_ROWS);
        }
    }
}

extern "C" void kernel_launch(void* const* d_in, const int* in_sizes, int n_in,
                              void* d_out, int out_size, void* d_ws, size_t ws_size,
                              hipStream_t stream) {
    const float* inp    = (const float*)d_in[0];
    const int*   target = (const int*)d_in[1];
    float*       out    = (float*)d_out;
    float*       rloss  = (float*)d_ws;                    // N_ROWS floats
    unsigned*    ticket = (unsigned*)((char*)d_ws + N_ROWS * sizeof(float));

    // zero the ticket every call (capture-safe async memset; ws is poisoned
    // to 0xAA before timing and never re-poisoned -> must not rely on it)
    hipMemsetAsync(ticket, 0, sizeof(unsigned), stream);

    focal_fused_kernel<<<N_ROWS, BLK, 0, stream>>>(inp, target, rloss, ticket, out);
}

// Round 4
// 85.167 us; speedup vs baseline: 4.9971x; 4.9971x over previous
//
#include <hip/hip_runtime.h>
#include <math.h>

#define N_ROWS 4096
#define N_COLS 32000
#define BLK 256

typedef float vf4 __attribute__((ext_vector_type(4)));

// gamma buckets: pt >= 0.5 -> 3, 0.2 <= pt < 0.5 -> 3, pt < 0.2 -> 5
// so gamma == 5 iff pt < 0.2, else 3.
//
// NOTE (R3 post-mortem): do NOT fuse the mean via per-block agent-scope
// acq_rel ticket atomics — each release/acquire emits an L2 writeback/
// invalidate, and 4096 of them destroy the streaming BW (88us -> 425us).
// Two plain dispatches is the right structure.

__device__ __forceinline__ void online_update(float& m, float& s, vf4 v) {
    float vmax = fmaxf(fmaxf(v.x, v.y), fmaxf(v.z, v.w));
    float nm = fmaxf(m, vmax);                 // branchless
    s = s * __expf(m - nm)
      + __expf(v.x - nm) + __expf(v.y - nm)
      + __expf(v.z - nm) + __expf(v.w - nm);
    m = nm;
}

__global__ __launch_bounds__(BLK) void focal_row_kernel(
    const float* __restrict__ inp,
    const int* __restrict__ target,
    float* __restrict__ row_loss)
{
    const int row = blockIdx.x;
    const int tid = threadIdx.x;
    const float* __restrict__ rp = inp + (size_t)row * N_COLS;
    const vf4* __restrict__ rp4 = (const vf4*)rp;
    const int nvec = N_COLS / 4;  // 8000, exact

    // two independent accumulator pairs -> deeper load pipeline
    float m0 = -3.0e38f, s0 = 0.0f;
    float m1 = -3.0e38f, s1 = 0.0f;

    int i = tid;
    for (; i + BLK < nvec; i += 2 * BLK) {
        vf4 a = __builtin_nontemporal_load(rp4 + i);
        vf4 b = __builtin_nontemporal_load(rp4 + i + BLK);
        online_update(m0, s0, a);
        online_update(m1, s1, b);
    }
    if (i < nvec) {
        vf4 a = __builtin_nontemporal_load(rp4 + i);
        online_update(m0, s0, a);
    }

    // merge the two accumulators
    float m = fmaxf(m0, m1);
    float s = s0 * __expf(m0 - m) + s1 * __expf(m1 - m);

    // ---- wave (64-lane) butterfly reduce of (m, s) ----
    #pragma unroll
    for (int off = 32; off > 0; off >>= 1) {
        float om = __shfl_xor(m, off, 64);
        float os = __shfl_xor(s, off, 64);
        float nm = fmaxf(m, om);
        s = s * __expf(m - nm) + os * __expf(om - nm);
        m = nm;
    }

    // ---- cross-wave combine via LDS (4 waves) ----
    __shared__ float sm[BLK / 64];
    __shared__ float ss[BLK / 64];
    if ((tid & 63) == 0) {
        sm[tid >> 6] = m;
        ss[tid >> 6] = s;
    }
    __syncthreads();

    if (tid == 0) {
        float M = sm[0];
        float S = ss[0];
        #pragma unroll
        for (int w = 1; w < BLK / 64; ++w) {
            float om = sm[w], os = ss[w];
            float nm = fmaxf(M, om);
            S = S * __expf(M - nm) + os * __expf(om - nm);
            M = nm;
        }
        const int t = target[row];
        const float x = rp[t];
        const float logpt = x - M - __logf(S);
        const float pt = __expf(logpt);
        const float u = 1.0f - pt;
        const float u3 = u * u * u;
        const float g = (pt < 0.2f) ? (u3 * u * u) : u3;  // (1-pt)^gamma
        row_loss[row] = -g * logpt;
    }
}

__global__ __launch_bounds__(BLK) void focal_reduce_kernel(
    const float* __restrict__ row_loss,
    float* __restrict__ out)
{
    const int tid = threadIdx.x;
    const vf4* __restrict__ rl4 = (const vf4*)row_loss;  // 1024 vec4
    float s = 0.0f;
    #pragma unroll
    for (int i = tid; i < N_ROWS / 4; i += BLK) {
        vf4 v = rl4[i];
        s += (v.x + v.y) + (v.z + v.w);
    }

    #pragma unroll
    for (int off = 32; off > 0; off >>= 1)
        s += __shfl_xor(s, off, 64);

    __shared__ float ws[BLK / 64];
    if ((tid & 63) == 0) ws[tid >> 6] = s;
    __syncthreads();

    if (tid == 0) {
        float acc = 0.0f;
        #pragma unroll
        for (int w = 0; w < BLK / 64; ++w) acc += ws[w];
        out[0] = acc * (1.0f / (float)N_ROWS);
    }
}

extern "C" void kernel_launch(void* const* d_in, const int* in_sizes, int n_in,
                              void* d_out, int out_size, void* d_ws, size_t ws_size,
                              hipStream_t stream) {
    const float* inp    = (const float*)d_in[0];
    const int*   target = (const int*)d_in[1];
    float*       out    = (float*)d_out;
    float*       rloss  = (float*)d_ws;  // N_ROWS floats of scratch

    focal_row_kernel<<<N_ROWS, BLK, 0, stream>>>(inp, target, rloss);
    focal_reduce_kernel<<<1, BLK, 0, stream>>>(rloss, out);
}